// Round 12
// baseline (1714.011 us; speedup 1.0000x reference)
//
#include <hip/hip_runtime.h>
#include <hip/hip_bf16.h>

#define SEQ 256
#define NB 16
#define HID 512
#define VOC 32000

typedef short bf16x8 __attribute__((ext_vector_type(8)));
typedef float f32x4 __attribute__((ext_vector_type(4)));
typedef unsigned long long u64;

__device__ __forceinline__ void ld_lds16(const void* g, void* l) {
  __builtin_amdgcn_global_load_lds((const __attribute__((address_space(1))) void*)g,
                                   (__attribute__((address_space(3))) void*)l, 16, 0, 0);
}

__device__ __forceinline__ unsigned pk2(float a, float b) {
  __hip_bfloat16 ha = __float2bfloat16(a), hb = __float2bfloat16(b);
  unsigned short ua = *(unsigned short*)&ha, ub = *(unsigned short*)&hb;
  return (unsigned)ua | ((unsigned)ub << 16);
}

__device__ __forceinline__ u64 agload(const u64* p) {
  return __hip_atomic_load(p, __ATOMIC_RELAXED, __HIP_MEMORY_SCOPE_AGENT);
}
__device__ __forceinline__ void agstore(u64* p, u64 v) {
  __hip_atomic_store(p, v, __ATOMIC_RELAXED, __HIP_MEMORY_SCOPE_AGENT);
}

// fast transcendentals (R11-proven: absmax unchanged). v_exp_f32 = 2^x.
__device__ __forceinline__ float fexp2(float x) {
  float r;
  asm("v_exp_f32 %0, %1" : "=v"(r) : "v"(x));
  return r;
}
__device__ __forceinline__ float frcp(float x) {
  float r;
  asm("v_rcp_f32 %0, %1" : "=v"(r) : "v"(x));
  return r;
}
__device__ __forceinline__ float fsig(float x) { return frcp(1.f + fexp2(-1.44269504f * x)); }
__device__ __forceinline__ float ftanh(float x) {
  return 1.f - 2.f * frcp(1.f + fexp2(2.88539008f * x));
}

// 16 staging u64s per lane: chunk s (0..3), j (0..3); addr = base + s*256 + j*16 (u64 units)
__device__ __forceinline__ void issue16(u64* q, const u64* base) {
#pragma unroll
  for (int s = 0; s < 4; ++s)
#pragma unroll
    for (int j = 0; j < 4; ++j) q[s * 4 + j] = agload(base + s * 256 + j * 16);
}
// sleep-free: reloads self-pace at the load RT; stale lanes only (R7 structure, no s_sleep)
__device__ __forceinline__ void revalidate16(u64* q, const u64* base, unsigned tg) {
  for (;;) {
    int bad = 0;
#pragma unroll
    for (int i = 0; i < 16; ++i) bad |= ((unsigned)(q[i] >> 32) != tg);
    if (!__any(bad)) break;
#pragma unroll
    for (int i = 0; i < 16; ++i)
      if ((unsigned)(q[i] >> 32) != tg)
        q[i] = agload(base + (i >> 2) * 256 + (i & 3) * 16);
  }
}

// 8 f32 -> bf16 hi + bf16 lo(residual)
__device__ __forceinline__ void cvt8_hilo(const float* p, bf16x8* h8, bf16x8* l8) {
  union { unsigned short u[8]; bf16x8 v; } uh, ul;
#pragma unroll
  for (int i = 0; i < 8; ++i) {
    float v = p[i];
    __hip_bfloat16 h = __float2bfloat16(v);
    uh.u[i] = *(unsigned short*)&h;
    float rem = v - __bfloat162float(h);
    __hip_bfloat16 l = __float2bfloat16(rem);
    ul.u[i] = *(unsigned short*)&l;
  }
  *h8 = uh.v;
  *l8 = ul.v;
}

// ---------------- embedding gather -> bf16, xe[t*16+b][512] ----------------
__global__ void embed_k(const int* __restrict__ x, const float* __restrict__ emb,
                        unsigned short* __restrict__ xe) {
  int bid = blockIdx.x;  // = t*16 + b
  int t = bid >> 4, b = bid & 15;
  int tok = x[b * SEQ + t];
  const float4* src = (const float4*)(emb + (size_t)tok * HID);
  int e = threadIdx.x;
  float4 a = src[e * 2], c = src[e * 2 + 1];
  uint4 o;
  o.x = pk2(a.x, a.y); o.y = pk2(a.z, a.w);
  o.z = pk2(c.x, c.y); o.w = pk2(c.z, c.w);
  ((uint4*)(xe + (size_t)bid * HID))[e] = o;
}

// ---------------- gx GEMM: gx[4096][2048] bf16 = xe @ Wih0^T (B cvt inline) ----------------
__global__ __launch_bounds__(256) void gx_gemm(const __hip_bfloat16* __restrict__ A,
                                               const float* __restrict__ Bw32,
                                               unsigned short* __restrict__ C) {
  __shared__ __align__(16) unsigned short lds_a[128 * 32];
  __shared__ __align__(16) unsigned short lds_b[128 * 32];
  const int tid = threadIdx.x;
  const int lane = tid & 63, wid = tid >> 6;
  const int m0 = blockIdx.y * 128, n0 = blockIdx.x * 128;
  const char* Ab = (const char*)A;
  const int ra = tid >> 2, cb = (tid & 3) * 16;
  f32x4 acc[4][4] = {};
  const int wm = (wid >> 1) * 64, wn = (wid & 1) * 64;
  const int fr = lane & 15, fk = (lane >> 4) * 8;
  for (int k0 = 0; k0 < HID; k0 += 32) {
    ld_lds16(Ab + (size_t)(m0 + ra) * 1024 + k0 * 2 + cb, (char*)lds_a + wid * 1024);
    ld_lds16(Ab + (size_t)(m0 + 64 + ra) * 1024 + k0 * 2 + cb, (char*)lds_a + 4096 + wid * 1024);
    {
      const float* p0 = Bw32 + (size_t)(n0 + ra) * HID + k0 + (tid & 3) * 8;
      const float* p1 = p0 + (size_t)64 * HID;
      float4 a0 = ((const float4*)p0)[0], a1 = ((const float4*)p0)[1];
      float4 b0 = ((const float4*)p1)[0], b1 = ((const float4*)p1)[1];
      uint4 pa = {pk2(a0.x, a0.y), pk2(a0.z, a0.w), pk2(a1.x, a1.y), pk2(a1.z, a1.w)};
      uint4 pb = {pk2(b0.x, b0.y), pk2(b0.z, b0.w), pk2(b1.x, b1.y), pk2(b1.z, b1.w)};
      ((uint4*)lds_b)[tid] = pa;
      ((uint4*)lds_b)[256 + tid] = pb;
    }
    __syncthreads();
    bf16x8 af[4], bf[4];
#pragma unroll
    for (int i = 0; i < 4; ++i) af[i] = *(const bf16x8*)&lds_a[(wm + i * 16 + fr) * 32 + fk];
#pragma unroll
    for (int j = 0; j < 4; ++j) bf[j] = *(const bf16x8*)&lds_b[(wn + j * 16 + fr) * 32 + fk];
#pragma unroll
    for (int i = 0; i < 4; ++i)
#pragma unroll
      for (int j = 0; j < 4; ++j)
        acc[i][j] = __builtin_amdgcn_mfma_f32_16x16x32_bf16(af[i], bf[j], acc[i][j], 0, 0, 0);
    __syncthreads();
  }
  const int cr = (lane >> 4) * 4, cc2 = lane & 15;
#pragma unroll
  for (int i = 0; i < 4; ++i)
#pragma unroll
    for (int jj = 0; jj < 4; ++jj) {
      size_t base = (size_t)(m0 + wm + i * 16 + cr) * 2048 + (n0 + wn + jj * 16 + cc2);
#pragma unroll
      for (int rr = 0; rr < 4; ++rr) {
        __hip_bfloat16 h = __float2bfloat16(acc[i][jj][rr]);
        C[base + (size_t)rr * 2048] = *(unsigned short*)&h;
      }
    }
}

// ---------------- persistent LSTM: R7 structure + fast gates + 1-barrier steps ----------------
// 256 blocks x 4 waves. lay = bid>>7, r8 = bid&127: 16 gate rows (4 cols x 4 gates).
// Wave wid owns k-slice [wid*128,+128). Weights reg-resident bf16 hi/lo.
// h handoff: u64 = {2 bf16 cols, tag=t+1}, relaxed agent store; consumer revalidates (no sleep).
// pbuf parity double-buffer -> single __syncthreads per step.
__global__ __launch_bounds__(256) void lstm_k(
    const float* __restrict__ Wih, const float* __restrict__ Whh,
    const float* __restrict__ bias, const unsigned short* __restrict__ gxb,
    u64* __restrict__ h0r, u64* __restrict__ h1r, unsigned short* __restrict__ outs) {
  __shared__ float pbuf[2][4][16][17];
  const int tid = threadIdx.x, bid = blockIdx.x;
  const int lay = bid >> 7, r8 = bid & 127;
  const int hc0 = r8 * 4;
  const int wid = tid >> 6, lane = tid & 63;
  const int b16 = lane & 15, hi = lane >> 4;

  // ---- weights -> registers (A row = lane&15, k = wid*128 + hi*8 + s*32) ----
  const int jrow = (b16 >> 2) * HID + hc0 + (b16 & 3);
  const int kb = wid * 128 + hi * 8;
  const float* wih_row = Wih + ((size_t)lay * 2048 + jrow) * HID;
  const float* whh_row = Whh + ((size_t)lay * 2048 + jrow) * HID;
  bf16x8 w0[4], w1[4], w2[4], w3[4];  // lay0: w0/w1 = Whh hi/lo. lay1: w0/w1 = Wih, w2/w3 = Whh
#pragma unroll
  for (int s = 0; s < 4; ++s) {
    if (lay == 0) {
      cvt8_hilo(whh_row + kb + s * 32, &w0[s], &w1[s]);
      w2[s] = w0[s]; w3[s] = w1[s];
    } else {
      cvt8_hilo(wih_row + kb + s * 32, &w0[s], &w1[s]);
      cvt8_hilo(whh_row + kb + s * 32, &w2[s], &w3[s]);
    }
  }
  const int eb = lane & 15, ehl = lane >> 4;  // epilogue map (wave0): batch, local col
  float bq[4];
#pragma unroll
  for (int q = 0; q < 4; ++q) bq[q] = bias[lay * 2048 + q * HID + hc0 + ehl];
  float c_reg = 0.f;
  const int lbase = wid * 1024 + hi * 64 + b16;  // u64 index within a 4096-u64 slot

#pragma unroll 1
  for (int t = 0; t < SEQ; ++t) {
    const int par = t & 1;
    f32x4 acc0 = {0.f, 0.f, 0.f, 0.f}, acc1 = {0.f, 0.f, 0.f, 0.f};
    float gxr[4] = {0.f, 0.f, 0.f, 0.f};
    if (lay == 0) {
      const u64* srcA = h0r + (size_t)t * 4096 + lbase;  // h0[t-1], tag t
      u64 qa[16];
      issue16(qa, srcA);
      if (wid == 0) {
        const unsigned short* gp = gxb + ((size_t)(t * 16 + eb)) * 2048 + hc0 + ehl;
#pragma unroll
        for (int q = 0; q < 4; ++q) {
          union { unsigned u; float f; } cv;
          cv.u = (unsigned)gp[q * HID] << 16;
          gxr[q] = cv.f;
        }
        asm volatile("" : "+v"(gxr[0]), "+v"(gxr[1]), "+v"(gxr[2]), "+v"(gxr[3]));
      }
      revalidate16(qa, srcA, (unsigned)t);
#pragma unroll
      for (int s = 0; s < 4; ++s) {
        union { unsigned u[4]; bf16x8 v; } bb;
#pragma unroll
        for (int j = 0; j < 4; ++j) bb.u[j] = (unsigned)qa[s * 4 + j];
        acc0 = __builtin_amdgcn_mfma_f32_16x16x32_bf16(w0[s], bb.v, acc0, 0, 0, 0);
        acc1 = __builtin_amdgcn_mfma_f32_16x16x32_bf16(w1[s], bb.v, acc1, 0, 0, 0);
      }
    } else {
      const u64* srcA = h0r + (size_t)(t + 1) * 4096 + lbase;  // h0[t], tag t+1
      const u64* srcB = h1r + (size_t)t * 4096 + lbase;        // h1[t-1], tag t
      u64 qb[16], qa[16];
      issue16(qb, srcB);
      issue16(qa, srcA);
      revalidate16(qb, srcB, (unsigned)t);
#pragma unroll
      for (int s = 0; s < 4; ++s) {
        union { unsigned u[4]; bf16x8 v; } bb;
#pragma unroll
        for (int j = 0; j < 4; ++j) bb.u[j] = (unsigned)qb[s * 4 + j];
        acc0 = __builtin_amdgcn_mfma_f32_16x16x32_bf16(w2[s], bb.v, acc0, 0, 0, 0);
        acc1 = __builtin_amdgcn_mfma_f32_16x16x32_bf16(w3[s], bb.v, acc1, 0, 0, 0);
      }
      revalidate16(qa, srcA, (unsigned)(t + 1));
#pragma unroll
      for (int s = 0; s < 4; ++s) {
        union { unsigned u[4]; bf16x8 v; } bb;
#pragma unroll
        for (int j = 0; j < 4; ++j) bb.u[j] = (unsigned)qa[s * 4 + j];
        acc0 = __builtin_amdgcn_mfma_f32_16x16x32_bf16(w0[s], bb.v, acc0, 0, 0, 0);
        acc1 = __builtin_amdgcn_mfma_f32_16x16x32_bf16(w1[s], bb.v, acc1, 0, 0, 0);
      }
    }
    f32x4 acc = acc0 + acc1;
#pragma unroll
    for (int rr = 0; rr < 4; ++rr) pbuf[par][wid][hi * 4 + rr][b16] = acc[rr];
    __syncthreads();  // single barrier per step (parity buffers protect reuse)

    // ---- epilogue: wave0 (64 lanes = 16 batches x 4 cols) ----
    if (wid == 0) {
      float pre[4];
#pragma unroll
      for (int q = 0; q < 4; ++q) {
        const int rl = q * 4 + ehl;
        pre[q] = bq[q] + gxr[q] + pbuf[par][0][rl][eb] + pbuf[par][1][rl][eb] +
                 pbuf[par][2][rl][eb] + pbuf[par][3][rl][eb];
      }
      float iv = fsig(pre[0]), fv = fsig(pre[1]);
      float gv = ftanh(pre[2]), ov = fsig(pre[3]);
      c_reg = fv * c_reg + iv * gv;
      float hn = ov * ftanh(c_reg);
      __hip_bfloat16 hh = __float2bfloat16(hn);
      int hb = (int)*(unsigned short*)&hh;
      int pr = __shfl_xor(hb, 16, 64);  // col ^ 1
      unsigned data32 = (unsigned)(unsigned short)hb | ((unsigned)(unsigned short)pr << 16);
      u64* ringo = (lay ? h1r : h0r) + (size_t)(t + 1) * 4096;
      if ((ehl & 1) == 0)
        agstore(ringo + (r8 * 2 + (ehl >> 1)) * 16 + eb,
                (u64)data32 | ((u64)(unsigned)(t + 1) << 32));
      if (lay) {
        unsigned d23 = (unsigned)__shfl((int)data32, eb + 32, 64);
        if (ehl == 0)
          *(u64*)(outs + ((size_t)(t * 16 + eb)) * 512 + hc0) = (u64)data32 | ((u64)d23 << 32);
      }
    }
  }
}

// ---------------- FC GEMM: out[b][t][32000] = outs[t*16+b][:] @ fcw^T + fcb ----------------
// B = fcw f32, converted to bf16 inline during staging (R11-proven path).
__global__ __launch_bounds__(256) void fc_gemm(const __hip_bfloat16* __restrict__ A,
                                               const float* __restrict__ Bw32,
                                               const float* __restrict__ bias,
                                               float* __restrict__ C) {
  __shared__ __align__(16) unsigned short lds_a[128 * 32];
  __shared__ __align__(16) unsigned short lds_b[128 * 32];
  const int tid = threadIdx.x;
  const int lane = tid & 63, wid = tid >> 6;
  const int m0 = blockIdx.y * 128, n0 = blockIdx.x * 128;
  const char* Ab = (const char*)A;
  const int ra = tid >> 2, cb = (tid & 3) * 16;
  f32x4 acc[4][4] = {};
  const int wm = (wid >> 1) * 64, wn = (wid & 1) * 64;
  const int fr = lane & 15, fk = (lane >> 4) * 8;
  for (int k0 = 0; k0 < HID; k0 += 32) {
    ld_lds16(Ab + (size_t)(m0 + ra) * 1024 + k0 * 2 + cb, (char*)lds_a + wid * 1024);
    ld_lds16(Ab + (size_t)(m0 + 64 + ra) * 1024 + k0 * 2 + cb, (char*)lds_a + 4096 + wid * 1024);
    {
      const float* p0 = Bw32 + (size_t)(n0 + ra) * HID + k0 + (tid & 3) * 8;
      const float* p1 = p0 + (size_t)64 * HID;
      float4 a0 = ((const float4*)p0)[0], a1 = ((const float4*)p0)[1];
      float4 b0 = ((const float4*)p1)[0], b1 = ((const float4*)p1)[1];
      uint4 pa = {pk2(a0.x, a0.y), pk2(a0.z, a0.w), pk2(a1.x, a1.y), pk2(a1.z, a1.w)};
      uint4 pb = {pk2(b0.x, b0.y), pk2(b0.z, b0.w), pk2(b1.x, b1.y), pk2(b1.z, b1.w)};
      ((uint4*)lds_b)[tid] = pa;
      ((uint4*)lds_b)[256 + tid] = pb;
    }
    __syncthreads();
    bf16x8 af[4], bf[4];
#pragma unroll
    for (int i = 0; i < 4; ++i) af[i] = *(const bf16x8*)&lds_a[(wm + i * 16 + fr) * 32 + fk];
#pragma unroll
    for (int j = 0; j < 4; ++j) bf[j] = *(const bf16x8*)&lds_b[(wn + j * 16 + fr) * 32 + fk];
#pragma unroll
    for (int i = 0; i < 4; ++i)
#pragma unroll
      for (int j = 0; j < 4; ++j)
        acc[i][j] = __builtin_amdgcn_mfma_f32_16x16x32_bf16(af[i], bf[j], acc[i][j], 0, 0, 0);
    __syncthreads();
  }
  const int cr = (lane >> 4) * 4, cc2 = lane & 15;
  float bv[4];
#pragma unroll
  for (int jj = 0; jj < 4; ++jj) bv[jj] = bias[n0 + wn + jj * 16 + cc2];
#pragma unroll
  for (int i = 0; i < 4; ++i) {
#pragma unroll
    for (int jj = 0; jj < 4; ++jj) {
#pragma unroll
      for (int rr = 0; rr < 4; ++rr) {
        int tok = m0 + wm + i * 16 + cr + rr;      // = t*16 + b
        int orow = (tok & 15) * SEQ + (tok >> 4);  // = b*256 + t
        C[(size_t)orow * VOC + (n0 + wn + jj * 16 + cc2)] = acc[i][jj][rr] + bv[jj];
      }
    }
  }
}

extern "C" void kernel_launch(void* const* d_in, const int* in_sizes, int n_in,
                              void* d_out, int out_size, void* d_ws, size_t ws_size,
                              hipStream_t stream) {
  const int* x = (const int*)d_in[0];
  const float* emb = (const float*)d_in[1];
  const float* Wih = (const float*)d_in[2];
  const float* Whh = (const float*)d_in[3];
  const float* bias = (const float*)d_in[4];
  const float* fcw = (const float*)d_in[5];
  const float* fcb = (const float*)d_in[6];
  float* out = (float*)d_out;
  char* ws = (char*)d_ws;

  // ws layout (bytes), total 42,008,576:
  //   [0, 8421376)            h0 ring: 257 slots x 32KB (u64 = 2 bf16 cols + tag)
  //   [8421376, 16842752)     h1 ring: 257 slots x 32KB
  //   [16842752, 21037056)    xe[4096][512] bf16
  //   [21037056, 37814272)    gx bf16 [4096][2048]
  //   [37814272, 42008576)    outs[4096][512] bf16
  u64* h0r = (u64*)ws;
  u64* h1r = (u64*)(ws + 8421376);
  unsigned short* xe = (unsigned short*)(ws + 16842752);
  unsigned short* gxb = (unsigned short*)(ws + 21037056);
  unsigned short* outs = (unsigned short*)(ws + 37814272);

  hipMemsetAsync(ws, 0, 16842752, stream);  // both rings: tags=0 (slot0 = valid zero h[-1])
  embed_k<<<SEQ * NB, 64, 0, stream>>>(x, emb, xe);
  gx_gemm<<<dim3(16, 32), 256, 0, stream>>>((const __hip_bfloat16*)xe, Wih, gxb);
  lstm_k<<<256, 256, 0, stream>>>(Wih, Whh, bias, gxb, h0r, h1r, outs);
  fc_gemm<<<dim3(250, 32), 256, 0, stream>>>((const __hip_bfloat16*)outs, fcw, fcb, out);
}

// Round 13
// 1296.304 us; speedup vs baseline: 1.3222x; 1.3222x over previous
//
#include <hip/hip_runtime.h>
#include <hip/hip_bf16.h>

#define SEQ 256
#define NB 16
#define HID 512
#define VOC 32000

typedef short bf16x8 __attribute__((ext_vector_type(8)));
typedef float f32x4 __attribute__((ext_vector_type(4)));
typedef unsigned long long u64;

__device__ __forceinline__ void ld_lds16(const void* g, void* l) {
  __builtin_amdgcn_global_load_lds((const __attribute__((address_space(1))) void*)g,
                                   (__attribute__((address_space(3))) void*)l, 16, 0, 0);
}

__device__ __forceinline__ unsigned pk2(float a, float b) {
  __hip_bfloat16 ha = __float2bfloat16(a), hb = __float2bfloat16(b);
  unsigned short ua = *(unsigned short*)&ha, ub = *(unsigned short*)&hb;
  return (unsigned)ua | ((unsigned)ub << 16);
}

__device__ __forceinline__ u64 agload(const u64* p) {
  return __hip_atomic_load(p, __ATOMIC_RELAXED, __HIP_MEMORY_SCOPE_AGENT);
}
__device__ __forceinline__ void agstore(u64* p, u64 v) {
  __hip_atomic_store(p, v, __ATOMIC_RELAXED, __HIP_MEMORY_SCOPE_AGENT);
}

// fast transcendentals (R11/R12-proven: absmax unchanged). v_exp_f32 = 2^x.
__device__ __forceinline__ float fexp2(float x) {
  float r;
  asm("v_exp_f32 %0, %1" : "=v"(r) : "v"(x));
  return r;
}
__device__ __forceinline__ float frcp(float x) {
  float r;
  asm("v_rcp_f32 %0, %1" : "=v"(r) : "v"(x));
  return r;
}
__device__ __forceinline__ float fsig(float x) { return frcp(1.f + fexp2(-1.44269504f * x)); }
__device__ __forceinline__ float ftanh(float x) {
  return 1.f - 2.f * frcp(1.f + fexp2(2.88539008f * x));
}

// 16 staging u64s per lane: chunk s (0..3), j (0..3); addr = base + s*256 + j*16 (u64 units)
__device__ __forceinline__ void issue16(u64* q, const u64* base) {
#pragma unroll
  for (int s = 0; s < 4; ++s)
#pragma unroll
    for (int j = 0; j < 4; ++j) q[s * 4 + j] = agload(base + s * 256 + j * 16);
}
// R7 revalidate: paced by s_sleep(1) — load-bearing (R12 refuted sleep-free)
__device__ __forceinline__ void revalidate16(u64* q, const u64* base, unsigned tg) {
  for (;;) {
    int bad = 0;
#pragma unroll
    for (int i = 0; i < 16; ++i) bad |= ((unsigned)(q[i] >> 32) != tg);
    if (!__any(bad)) break;
    __builtin_amdgcn_s_sleep(1);
#pragma unroll
    for (int i = 0; i < 16; ++i)
      if ((unsigned)(q[i] >> 32) != tg)
        q[i] = agload(base + (i >> 2) * 256 + (i & 3) * 16);
  }
}

// 8 f32 -> bf16 hi + bf16 lo(residual)
__device__ __forceinline__ void cvt8_hilo(const float* p, bf16x8* h8, bf16x8* l8) {
  union { unsigned short u[8]; bf16x8 v; } uh, ul;
#pragma unroll
  for (int i = 0; i < 8; ++i) {
    float v = p[i];
    __hip_bfloat16 h = __float2bfloat16(v);
    uh.u[i] = *(unsigned short*)&h;
    float rem = v - __bfloat162float(h);
    __hip_bfloat16 l = __float2bfloat16(rem);
    ul.u[i] = *(unsigned short*)&l;
  }
  *h8 = uh.v;
  *l8 = ul.v;
}

// ---------------- embedding gather -> bf16, xe[t*16+b][512] ----------------
__global__ void embed_k(const int* __restrict__ x, const float* __restrict__ emb,
                        unsigned short* __restrict__ xe) {
  int bid = blockIdx.x;  // = t*16 + b
  int t = bid >> 4, b = bid & 15;
  int tok = x[b * SEQ + t];
  const float4* src = (const float4*)(emb + (size_t)tok * HID);
  int e = threadIdx.x;
  float4 a = src[e * 2], c = src[e * 2 + 1];
  uint4 o;
  o.x = pk2(a.x, a.y); o.y = pk2(a.z, a.w);
  o.z = pk2(c.x, c.y); o.w = pk2(c.z, c.w);
  ((uint4*)(xe + (size_t)bid * HID))[e] = o;
}

// ---------------- gx GEMM: gx[4096][2048] bf16 = xe @ Wih0^T (B cvt inline) ----------------
__global__ __launch_bounds__(256) void gx_gemm(const __hip_bfloat16* __restrict__ A,
                                               const float* __restrict__ Bw32,
                                               unsigned short* __restrict__ C) {
  __shared__ __align__(16) unsigned short lds_a[128 * 32];
  __shared__ __align__(16) unsigned short lds_b[128 * 32];
  const int tid = threadIdx.x;
  const int lane = tid & 63, wid = tid >> 6;
  const int m0 = blockIdx.y * 128, n0 = blockIdx.x * 128;
  const char* Ab = (const char*)A;
  const int ra = tid >> 2, cb = (tid & 3) * 16;
  f32x4 acc[4][4] = {};
  const int wm = (wid >> 1) * 64, wn = (wid & 1) * 64;
  const int fr = lane & 15, fk = (lane >> 4) * 8;
  for (int k0 = 0; k0 < HID; k0 += 32) {
    ld_lds16(Ab + (size_t)(m0 + ra) * 1024 + k0 * 2 + cb, (char*)lds_a + wid * 1024);
    ld_lds16(Ab + (size_t)(m0 + 64 + ra) * 1024 + k0 * 2 + cb, (char*)lds_a + 4096 + wid * 1024);
    {
      const float* p0 = Bw32 + (size_t)(n0 + ra) * HID + k0 + (tid & 3) * 8;
      const float* p1 = p0 + (size_t)64 * HID;
      float4 a0 = ((const float4*)p0)[0], a1 = ((const float4*)p0)[1];
      float4 b0 = ((const float4*)p1)[0], b1 = ((const float4*)p1)[1];
      uint4 pa = {pk2(a0.x, a0.y), pk2(a0.z, a0.w), pk2(a1.x, a1.y), pk2(a1.z, a1.w)};
      uint4 pb = {pk2(b0.x, b0.y), pk2(b0.z, b0.w), pk2(b1.x, b1.y), pk2(b1.z, b1.w)};
      ((uint4*)lds_b)[tid] = pa;
      ((uint4*)lds_b)[256 + tid] = pb;
    }
    __syncthreads();
    bf16x8 af[4], bf[4];
#pragma unroll
    for (int i = 0; i < 4; ++i) af[i] = *(const bf16x8*)&lds_a[(wm + i * 16 + fr) * 32 + fk];
#pragma unroll
    for (int j = 0; j < 4; ++j) bf[j] = *(const bf16x8*)&lds_b[(wn + j * 16 + fr) * 32 + fk];
#pragma unroll
    for (int i = 0; i < 4; ++i)
#pragma unroll
      for (int j = 0; j < 4; ++j)
        acc[i][j] = __builtin_amdgcn_mfma_f32_16x16x32_bf16(af[i], bf[j], acc[i][j], 0, 0, 0);
    __syncthreads();
  }
  const int cr = (lane >> 4) * 4, cc2 = lane & 15;
#pragma unroll
  for (int i = 0; i < 4; ++i)
#pragma unroll
    for (int jj = 0; jj < 4; ++jj) {
      size_t base = (size_t)(m0 + wm + i * 16 + cr) * 2048 + (n0 + wn + jj * 16 + cc2);
#pragma unroll
      for (int rr = 0; rr < 4; ++rr) {
        __hip_bfloat16 h = __float2bfloat16(acc[i][jj][rr]);
        C[base + (size_t)rr * 2048] = *(unsigned short*)&h;
      }
    }
}

// ---------------- persistent LSTM: R7 structure VERBATIM + fast gates ----------------
// 256 blocks x 4 waves. lay = bid>>7, r8 = bid&127: 16 gate rows (4 cols x 4 gates).
// Wave wid owns k-slice [wid*128,+128). Weights reg-resident bf16 hi/lo.
// h handoff: u64 = {2 bf16 cols, tag=t+1}, relaxed agent store; consumer issue+revalidate
// (s_sleep(1)-paced). Two __syncthreads per step (R12 refuted the 1-barrier variant).
__global__ __launch_bounds__(256) void lstm_k(
    const float* __restrict__ Wih, const float* __restrict__ Whh,
    const float* __restrict__ bias, const unsigned short* __restrict__ gxb,
    u64* __restrict__ h0r, u64* __restrict__ h1r, unsigned short* __restrict__ outs) {
  __shared__ float pbuf[4][16][17];
  const int tid = threadIdx.x, bid = blockIdx.x;
  const int lay = bid >> 7, r8 = bid & 127;
  const int hc0 = r8 * 4;
  const int wid = tid >> 6, lane = tid & 63;
  const int b16 = lane & 15, hi = lane >> 4;

  // ---- weights -> registers (A row = lane&15, k = wid*128 + hi*8 + s*32) ----
  const int jrow = (b16 >> 2) * HID + hc0 + (b16 & 3);
  const int kb = wid * 128 + hi * 8;
  const float* wih_row = Wih + ((size_t)lay * 2048 + jrow) * HID;
  const float* whh_row = Whh + ((size_t)lay * 2048 + jrow) * HID;
  bf16x8 w0[4], w1[4], w2[4], w3[4];  // lay0: w0/w1 = Whh hi/lo. lay1: w0/w1 = Wih, w2/w3 = Whh
#pragma unroll
  for (int s = 0; s < 4; ++s) {
    if (lay == 0) {
      cvt8_hilo(whh_row + kb + s * 32, &w0[s], &w1[s]);
      w2[s] = w0[s]; w3[s] = w1[s];
    } else {
      cvt8_hilo(wih_row + kb + s * 32, &w0[s], &w1[s]);
      cvt8_hilo(whh_row + kb + s * 32, &w2[s], &w3[s]);
    }
  }
  const int eb = lane & 15, ehl = lane >> 4;  // epilogue map (wave0): batch, local col
  float bq[4];
#pragma unroll
  for (int q = 0; q < 4; ++q) bq[q] = bias[lay * 2048 + q * HID + hc0 + ehl];
  float c_reg = 0.f;
  const int lbase = wid * 1024 + hi * 64 + b16;  // u64 index within a 4096-u64 slot

#pragma unroll 1
  for (int t = 0; t < SEQ; ++t) {
    f32x4 acc0 = {0.f, 0.f, 0.f, 0.f}, acc1 = {0.f, 0.f, 0.f, 0.f};
    float gxr[4] = {0.f, 0.f, 0.f, 0.f};
    if (lay == 0) {
      const u64* srcA = h0r + (size_t)t * 4096 + lbase;  // h0[t-1], tag t
      u64 qa[16];
      issue16(qa, srcA);
      if (wid == 0) {
        const unsigned short* gp = gxb + ((size_t)(t * 16 + eb)) * 2048 + hc0 + ehl;
#pragma unroll
        for (int q = 0; q < 4; ++q) {
          union { unsigned u; float f; } cv;
          cv.u = (unsigned)gp[q * HID] << 16;
          gxr[q] = cv.f;
        }
        asm volatile("" : "+v"(gxr[0]), "+v"(gxr[1]), "+v"(gxr[2]), "+v"(gxr[3]));
      }
      revalidate16(qa, srcA, (unsigned)t);
#pragma unroll
      for (int s = 0; s < 4; ++s) {
        union { unsigned u[4]; bf16x8 v; } bb;
#pragma unroll
        for (int j = 0; j < 4; ++j) bb.u[j] = (unsigned)qa[s * 4 + j];
        acc0 = __builtin_amdgcn_mfma_f32_16x16x32_bf16(w0[s], bb.v, acc0, 0, 0, 0);
        acc1 = __builtin_amdgcn_mfma_f32_16x16x32_bf16(w1[s], bb.v, acc1, 0, 0, 0);
      }
    } else {
      const u64* srcA = h0r + (size_t)(t + 1) * 4096 + lbase;  // h0[t], tag t+1
      const u64* srcB = h1r + (size_t)t * 4096 + lbase;        // h1[t-1], tag t
      u64 qb[16], qa[16];
      issue16(qb, srcB);
      issue16(qa, srcA);
      revalidate16(qb, srcB, (unsigned)t);
#pragma unroll
      for (int s = 0; s < 4; ++s) {
        union { unsigned u[4]; bf16x8 v; } bb;
#pragma unroll
        for (int j = 0; j < 4; ++j) bb.u[j] = (unsigned)qb[s * 4 + j];
        acc0 = __builtin_amdgcn_mfma_f32_16x16x32_bf16(w2[s], bb.v, acc0, 0, 0, 0);
        acc1 = __builtin_amdgcn_mfma_f32_16x16x32_bf16(w3[s], bb.v, acc1, 0, 0, 0);
      }
      revalidate16(qa, srcA, (unsigned)(t + 1));
#pragma unroll
      for (int s = 0; s < 4; ++s) {
        union { unsigned u[4]; bf16x8 v; } bb;
#pragma unroll
        for (int j = 0; j < 4; ++j) bb.u[j] = (unsigned)qa[s * 4 + j];
        acc0 = __builtin_amdgcn_mfma_f32_16x16x32_bf16(w0[s], bb.v, acc0, 0, 0, 0);
        acc1 = __builtin_amdgcn_mfma_f32_16x16x32_bf16(w1[s], bb.v, acc1, 0, 0, 0);
      }
    }
    f32x4 acc = acc0 + acc1;
#pragma unroll
    for (int rr = 0; rr < 4; ++rr) pbuf[wid][hi * 4 + rr][b16] = acc[rr];
    __syncthreads();

    // ---- epilogue: wave0 (64 lanes = 16 batches x 4 cols) ----
    if (wid == 0) {
      float pre[4];
#pragma unroll
      for (int q = 0; q < 4; ++q) {
        const int rl = q * 4 + ehl;
        pre[q] = bq[q] + gxr[q] + pbuf[0][rl][eb] + pbuf[1][rl][eb] +
                 pbuf[2][rl][eb] + pbuf[3][rl][eb];
      }
      float iv = fsig(pre[0]), fv = fsig(pre[1]);
      float gv = ftanh(pre[2]), ov = fsig(pre[3]);
      c_reg = fv * c_reg + iv * gv;
      float hn = ov * ftanh(c_reg);
      __hip_bfloat16 hh = __float2bfloat16(hn);
      int hb = (int)*(unsigned short*)&hh;
      int pr = __shfl_xor(hb, 16, 64);  // col ^ 1
      unsigned data32 = (unsigned)(unsigned short)hb | ((unsigned)(unsigned short)pr << 16);
      u64* ringo = (lay ? h1r : h0r) + (size_t)(t + 1) * 4096;
      if ((ehl & 1) == 0)
        agstore(ringo + (r8 * 2 + (ehl >> 1)) * 16 + eb,
                (u64)data32 | ((u64)(unsigned)(t + 1) << 32));
      if (lay) {
        unsigned d23 = (unsigned)__shfl((int)data32, eb + 32, 64);
        if (ehl == 0)
          *(u64*)(outs + ((size_t)(t * 16 + eb)) * 512 + hc0) = (u64)data32 | ((u64)d23 << 32);
      }
    }
    __syncthreads();  // pbuf reuse guard (R7 structure)
  }
}

// ---------------- FC GEMM: out[b][t][32000] = outs[t*16+b][:] @ fcw^T + fcb ----------------
// B = fcw f32, converted to bf16 inline during staging (R11/R12-proven path).
__global__ __launch_bounds__(256) void fc_gemm(const __hip_bfloat16* __restrict__ A,
                                               const float* __restrict__ Bw32,
                                               const float* __restrict__ bias,
                                               float* __restrict__ C) {
  __shared__ __align__(16) unsigned short lds_a[128 * 32];
  __shared__ __align__(16) unsigned short lds_b[128 * 32];
  const int tid = threadIdx.x;
  const int lane = tid & 63, wid = tid >> 6;
  const int m0 = blockIdx.y * 128, n0 = blockIdx.x * 128;
  const char* Ab = (const char*)A;
  const int ra = tid >> 2, cb = (tid & 3) * 16;
  f32x4 acc[4][4] = {};
  const int wm = (wid >> 1) * 64, wn = (wid & 1) * 64;
  const int fr = lane & 15, fk = (lane >> 4) * 8;
  for (int k0 = 0; k0 < HID; k0 += 32) {
    ld_lds16(Ab + (size_t)(m0 + ra) * 1024 + k0 * 2 + cb, (char*)lds_a + wid * 1024);
    ld_lds16(Ab + (size_t)(m0 + 64 + ra) * 1024 + k0 * 2 + cb, (char*)lds_a + 4096 + wid * 1024);
    {
      const float* p0 = Bw32 + (size_t)(n0 + ra) * HID + k0 + (tid & 3) * 8;
      const float* p1 = p0 + (size_t)64 * HID;
      float4 a0 = ((const float4*)p0)[0], a1 = ((const float4*)p0)[1];
      float4 b0 = ((const float4*)p1)[0], b1 = ((const float4*)p1)[1];
      uint4 pa = {pk2(a0.x, a0.y), pk2(a0.z, a0.w), pk2(a1.x, a1.y), pk2(a1.z, a1.w)};
      uint4 pb = {pk2(b0.x, b0.y), pk2(b0.z, b0.w), pk2(b1.x, b1.y), pk2(b1.z, b1.w)};
      ((uint4*)lds_b)[tid] = pa;
      ((uint4*)lds_b)[256 + tid] = pb;
    }
    __syncthreads();
    bf16x8 af[4], bf[4];
#pragma unroll
    for (int i = 0; i < 4; ++i) af[i] = *(const bf16x8*)&lds_a[(wm + i * 16 + fr) * 32 + fk];
#pragma unroll
    for (int j = 0; j < 4; ++j) bf[j] = *(const bf16x8*)&lds_b[(wn + j * 16 + fr) * 32 + fk];
#pragma unroll
    for (int i = 0; i < 4; ++i)
#pragma unroll
      for (int j = 0; j < 4; ++j)
        acc[i][j] = __builtin_amdgcn_mfma_f32_16x16x32_bf16(af[i], bf[j], acc[i][j], 0, 0, 0);
    __syncthreads();
  }
  const int cr = (lane >> 4) * 4, cc2 = lane & 15;
  float bv[4];
#pragma unroll
  for (int jj = 0; jj < 4; ++jj) bv[jj] = bias[n0 + wn + jj * 16 + cc2];
#pragma unroll
  for (int i = 0; i < 4; ++i) {
#pragma unroll
    for (int jj = 0; jj < 4; ++jj) {
#pragma unroll
      for (int rr = 0; rr < 4; ++rr) {
        int tok = m0 + wm + i * 16 + cr + rr;      // = t*16 + b
        int orow = (tok & 15) * SEQ + (tok >> 4);  // = b*256 + t
        C[(size_t)orow * VOC + (n0 + wn + jj * 16 + cc2)] = acc[i][jj][rr] + bv[jj];
      }
    }
  }
}

extern "C" void kernel_launch(void* const* d_in, const int* in_sizes, int n_in,
                              void* d_out, int out_size, void* d_ws, size_t ws_size,
                              hipStream_t stream) {
  const int* x = (const int*)d_in[0];
  const float* emb = (const float*)d_in[1];
  const float* Wih = (const float*)d_in[2];
  const float* Whh = (const float*)d_in[3];
  const float* bias = (const float*)d_in[4];
  const float* fcw = (const float*)d_in[5];
  const float* fcb = (const float*)d_in[6];
  float* out = (float*)d_out;
  char* ws = (char*)d_ws;

  // ws layout (bytes), total 42,008,576:
  //   [0, 8421376)            h0 ring: 257 slots x 32KB (u64 = 2 bf16 cols + tag)
  //   [8421376, 16842752)     h1 ring: 257 slots x 32KB
  //   [16842752, 21037056)    xe[4096][512] bf16
  //   [21037056, 37814272)    gx bf16 [4096][2048]
  //   [37814272, 42008576)    outs[4096][512] bf16
  u64* h0r = (u64*)ws;
  u64* h1r = (u64*)(ws + 8421376);
  unsigned short* xe = (unsigned short*)(ws + 16842752);
  unsigned short* gxb = (unsigned short*)(ws + 21037056);
  unsigned short* outs = (unsigned short*)(ws + 37814272);

  hipMemsetAsync(ws, 0, 16842752, stream);  // both rings: tags=0 (slot0 = valid zero h[-1])
  embed_k<<<SEQ * NB, 64, 0, stream>>>(x, emb, xe);
  gx_gemm<<<dim3(16, 32), 256, 0, stream>>>((const __hip_bfloat16*)xe, Wih, gxb);
  lstm_k<<<256, 256, 0, stream>>>(Wih, Whh, bias, gxb, h0r, h1r, outs);
  fc_gemm<<<dim3(250, 32), 256, 0, stream>>>((const __hip_bfloat16*)outs, fcw, fcb, out);
}

// Round 14
// 1169.857 us; speedup vs baseline: 1.4651x; 1.1081x over previous
//
#include <hip/hip_runtime.h>
#include <hip/hip_bf16.h>

#define SEQ 256
#define NB 16
#define HID 512
#define VOC 32000

typedef short bf16x8 __attribute__((ext_vector_type(8)));
typedef float f32x4 __attribute__((ext_vector_type(4)));
typedef unsigned long long u64;

__device__ __forceinline__ void ld_lds16(const void* g, void* l) {
  __builtin_amdgcn_global_load_lds((const __attribute__((address_space(1))) void*)g,
                                   (__attribute__((address_space(3))) void*)l, 16, 0, 0);
}

__device__ __forceinline__ unsigned pk2(float a, float b) {
  __hip_bfloat16 ha = __float2bfloat16(a), hb = __float2bfloat16(b);
  unsigned short ua = *(unsigned short*)&ha, ub = *(unsigned short*)&hb;
  return (unsigned)ua | ((unsigned)ub << 16);
}

__device__ __forceinline__ u64 agload(const u64* p) {
  return __hip_atomic_load(p, __ATOMIC_RELAXED, __HIP_MEMORY_SCOPE_AGENT);
}
__device__ __forceinline__ void agstore(u64* p, u64 v) {
  __hip_atomic_store(p, v, __ATOMIC_RELAXED, __HIP_MEMORY_SCOPE_AGENT);
}

// fast transcendentals (R11-R13 proven: absmax unchanged). v_exp_f32 = 2^x.
__device__ __forceinline__ float fexp2(float x) {
  float r;
  asm("v_exp_f32 %0, %1" : "=v"(r) : "v"(x));
  return r;
}
__device__ __forceinline__ float frcp(float x) {
  float r;
  asm("v_rcp_f32 %0, %1" : "=v"(r) : "v"(x));
  return r;
}
__device__ __forceinline__ float fsig(float x) { return frcp(1.f + fexp2(-1.44269504f * x)); }
__device__ __forceinline__ float ftanh(float x) {
  return 1.f - 2.f * frcp(1.f + fexp2(2.88539008f * x));
}

// 16 staging u64s per lane: chunk s (0..3), j (0..3); addr = base + s*256 + j*16 (u64 units)
__device__ __forceinline__ void issue16(u64* q, const u64* base) {
#pragma unroll
  for (int s = 0; s < 4; ++s)
#pragma unroll
    for (int j = 0; j < 4; ++j) q[s * 4 + j] = agload(base + s * 256 + j * 16);
}
// R7 revalidate: s_sleep(1)-paced (load-bearing; sleep-free refuted R12, sentinel refuted R8)
__device__ __forceinline__ void revalidate16(u64* q, const u64* base, unsigned tg) {
  for (;;) {
    int bad = 0;
#pragma unroll
    for (int i = 0; i < 16; ++i) bad |= ((unsigned)(q[i] >> 32) != tg);
    if (!__any(bad)) break;
    __builtin_amdgcn_s_sleep(1);
#pragma unroll
    for (int i = 0; i < 16; ++i)
      if ((unsigned)(q[i] >> 32) != tg)
        q[i] = agload(base + (i >> 2) * 256 + (i & 3) * 16);
  }
}

// 8 f32 -> bf16 hi + bf16 lo(residual)
__device__ __forceinline__ void cvt8_hilo(const float* p, bf16x8* h8, bf16x8* l8) {
  union { unsigned short u[8]; bf16x8 v; } uh, ul;
#pragma unroll
  for (int i = 0; i < 8; ++i) {
    float v = p[i];
    __hip_bfloat16 h = __float2bfloat16(v);
    uh.u[i] = *(unsigned short*)&h;
    float rem = v - __bfloat162float(h);
    __hip_bfloat16 l = __float2bfloat16(rem);
    ul.u[i] = *(unsigned short*)&l;
  }
  *h8 = uh.v;
  *l8 = ul.v;
}

// ---------------- embedding gather -> bf16, xe[t*16+b][512] ----------------
__global__ void embed_k(const int* __restrict__ x, const float* __restrict__ emb,
                        unsigned short* __restrict__ xe) {
  int bid = blockIdx.x;  // = t*16 + b
  int t = bid >> 4, b = bid & 15;
  int tok = x[b * SEQ + t];
  const float4* src = (const float4*)(emb + (size_t)tok * HID);
  int e = threadIdx.x;
  float4 a = src[e * 2], c = src[e * 2 + 1];
  uint4 o;
  o.x = pk2(a.x, a.y); o.y = pk2(a.z, a.w);
  o.z = pk2(c.x, c.y); o.w = pk2(c.z, c.w);
  ((uint4*)(xe + (size_t)bid * HID))[e] = o;
}

// ---------------- f32 -> bf16 pack, 8/thread ----------------
__global__ void cvt_k(const float* __restrict__ in, uint4* __restrict__ out) {
  size_t i = (size_t)blockIdx.x * blockDim.x + threadIdx.x;
  const float4* in4 = (const float4*)in;
  float4 a = in4[i * 2], b = in4[i * 2 + 1];
  uint4 o;
  o.x = pk2(a.x, a.y); o.y = pk2(a.z, a.w);
  o.z = pk2(b.x, b.y); o.w = pk2(b.z, b.w);
  out[i] = o;
}

// ---------------- gx GEMM: gx[4096][2048] bf16 = xe @ Wih0^T (bf16 B, R7-proven) ----------------
__global__ __launch_bounds__(256) void gx_gemm(const __hip_bfloat16* __restrict__ A,
                                               const __hip_bfloat16* __restrict__ Bw,
                                               unsigned short* __restrict__ C) {
  __shared__ __align__(16) unsigned short lds_a[128 * 32];
  __shared__ __align__(16) unsigned short lds_b[128 * 32];
  const int tid = threadIdx.x;
  const int lane = tid & 63, wid = tid >> 6;
  const int m0 = blockIdx.y * 128, n0 = blockIdx.x * 128;
  const char* Ab = (const char*)A;
  const char* Bb = (const char*)Bw;
  const int ra = tid >> 2, cb = (tid & 3) * 16;
  f32x4 acc[4][4] = {};
  const int wm = (wid >> 1) * 64, wn = (wid & 1) * 64;
  const int fr = lane & 15, fk = (lane >> 4) * 8;
  for (int k0 = 0; k0 < HID; k0 += 32) {
    ld_lds16(Ab + (size_t)(m0 + ra) * 1024 + k0 * 2 + cb, (char*)lds_a + wid * 1024);
    ld_lds16(Ab + (size_t)(m0 + 64 + ra) * 1024 + k0 * 2 + cb, (char*)lds_a + 4096 + wid * 1024);
    ld_lds16(Bb + (size_t)(n0 + ra) * 1024 + k0 * 2 + cb, (char*)lds_b + wid * 1024);
    ld_lds16(Bb + (size_t)(n0 + 64 + ra) * 1024 + k0 * 2 + cb, (char*)lds_b + 4096 + wid * 1024);
    __syncthreads();
    bf16x8 af[4], bf[4];
#pragma unroll
    for (int i = 0; i < 4; ++i) af[i] = *(const bf16x8*)&lds_a[(wm + i * 16 + fr) * 32 + fk];
#pragma unroll
    for (int j = 0; j < 4; ++j) bf[j] = *(const bf16x8*)&lds_b[(wn + j * 16 + fr) * 32 + fk];
#pragma unroll
    for (int i = 0; i < 4; ++i)
#pragma unroll
      for (int j = 0; j < 4; ++j)
        acc[i][j] = __builtin_amdgcn_mfma_f32_16x16x32_bf16(af[i], bf[j], acc[i][j], 0, 0, 0);
    __syncthreads();
  }
  const int cr = (lane >> 4) * 4, cc2 = lane & 15;
#pragma unroll
  for (int i = 0; i < 4; ++i)
#pragma unroll
    for (int jj = 0; jj < 4; ++jj) {
      size_t base = (size_t)(m0 + wm + i * 16 + cr) * 2048 + (n0 + wn + jj * 16 + cc2);
#pragma unroll
      for (int rr = 0; rr < 4; ++rr) {
        __hip_bfloat16 h = __float2bfloat16(acc[i][jj][rr]);
        C[base + (size_t)rr * 2048] = *(unsigned short*)&h;
      }
    }
}

// ---------------- persistent LSTM: R7 protocol + fast gates (R13-proven, 880us) ----------------
// 256 blocks x 4 waves. lay = bid>>7, r8 = bid&127: 16 gate rows (4 cols x 4 gates).
// Wave wid owns k-slice [wid*128,+128). Weights reg-resident bf16 hi/lo.
// h handoff: u64 = {2 bf16 cols, tag=t+1}, relaxed agent store; consumer issue+revalidate.
__global__ __launch_bounds__(256) void lstm_k(
    const float* __restrict__ Wih, const float* __restrict__ Whh,
    const float* __restrict__ bias, const unsigned short* __restrict__ gxb,
    u64* __restrict__ h0r, u64* __restrict__ h1r, unsigned short* __restrict__ outs) {
  __shared__ float pbuf[4][16][17];
  const int tid = threadIdx.x, bid = blockIdx.x;
  const int lay = bid >> 7, r8 = bid & 127;
  const int hc0 = r8 * 4;
  const int wid = tid >> 6, lane = tid & 63;
  const int b16 = lane & 15, hi = lane >> 4;

  const int jrow = (b16 >> 2) * HID + hc0 + (b16 & 3);
  const int kb = wid * 128 + hi * 8;
  const float* wih_row = Wih + ((size_t)lay * 2048 + jrow) * HID;
  const float* whh_row = Whh + ((size_t)lay * 2048 + jrow) * HID;
  bf16x8 w0[4], w1[4], w2[4], w3[4];  // lay0: w0/w1 = Whh hi/lo. lay1: w0/w1 = Wih, w2/w3 = Whh
#pragma unroll
  for (int s = 0; s < 4; ++s) {
    if (lay == 0) {
      cvt8_hilo(whh_row + kb + s * 32, &w0[s], &w1[s]);
      w2[s] = w0[s]; w3[s] = w1[s];
    } else {
      cvt8_hilo(wih_row + kb + s * 32, &w0[s], &w1[s]);
      cvt8_hilo(whh_row + kb + s * 32, &w2[s], &w3[s]);
    }
  }
  const int eb = lane & 15, ehl = lane >> 4;  // epilogue map (wave0): batch, local col
  float bq[4];
#pragma unroll
  for (int q = 0; q < 4; ++q) bq[q] = bias[lay * 2048 + q * HID + hc0 + ehl];
  float c_reg = 0.f;
  const int lbase = wid * 1024 + hi * 64 + b16;  // u64 index within a 4096-u64 slot

#pragma unroll 1
  for (int t = 0; t < SEQ; ++t) {
    f32x4 acc0 = {0.f, 0.f, 0.f, 0.f}, acc1 = {0.f, 0.f, 0.f, 0.f};
    float gxr[4] = {0.f, 0.f, 0.f, 0.f};
    if (lay == 0) {
      const u64* srcA = h0r + (size_t)t * 4096 + lbase;  // h0[t-1], tag t
      u64 qa[16];
      issue16(qa, srcA);
      if (wid == 0) {
        const unsigned short* gp = gxb + ((size_t)(t * 16 + eb)) * 2048 + hc0 + ehl;
#pragma unroll
        for (int q = 0; q < 4; ++q) {
          union { unsigned u; float f; } cv;
          cv.u = (unsigned)gp[q * HID] << 16;
          gxr[q] = cv.f;
        }
        asm volatile("" : "+v"(gxr[0]), "+v"(gxr[1]), "+v"(gxr[2]), "+v"(gxr[3]));
      }
      revalidate16(qa, srcA, (unsigned)t);
#pragma unroll
      for (int s = 0; s < 4; ++s) {
        union { unsigned u[4]; bf16x8 v; } bb;
#pragma unroll
        for (int j = 0; j < 4; ++j) bb.u[j] = (unsigned)qa[s * 4 + j];
        acc0 = __builtin_amdgcn_mfma_f32_16x16x32_bf16(w0[s], bb.v, acc0, 0, 0, 0);
        acc1 = __builtin_amdgcn_mfma_f32_16x16x32_bf16(w1[s], bb.v, acc1, 0, 0, 0);
      }
    } else {
      const u64* srcA = h0r + (size_t)(t + 1) * 4096 + lbase;  // h0[t], tag t+1
      const u64* srcB = h1r + (size_t)t * 4096 + lbase;        // h1[t-1], tag t
      u64 qb[16], qa[16];
      issue16(qb, srcB);
      issue16(qa, srcA);
      revalidate16(qb, srcB, (unsigned)t);
#pragma unroll
      for (int s = 0; s < 4; ++s) {
        union { unsigned u[4]; bf16x8 v; } bb;
#pragma unroll
        for (int j = 0; j < 4; ++j) bb.u[j] = (unsigned)qb[s * 4 + j];
        acc0 = __builtin_amdgcn_mfma_f32_16x16x32_bf16(w2[s], bb.v, acc0, 0, 0, 0);
        acc1 = __builtin_amdgcn_mfma_f32_16x16x32_bf16(w3[s], bb.v, acc1, 0, 0, 0);
      }
      revalidate16(qa, srcA, (unsigned)(t + 1));
#pragma unroll
      for (int s = 0; s < 4; ++s) {
        union { unsigned u[4]; bf16x8 v; } bb;
#pragma unroll
        for (int j = 0; j < 4; ++j) bb.u[j] = (unsigned)qa[s * 4 + j];
        acc0 = __builtin_amdgcn_mfma_f32_16x16x32_bf16(w0[s], bb.v, acc0, 0, 0, 0);
        acc1 = __builtin_amdgcn_mfma_f32_16x16x32_bf16(w1[s], bb.v, acc1, 0, 0, 0);
      }
    }
    f32x4 acc = acc0 + acc1;
#pragma unroll
    for (int rr = 0; rr < 4; ++rr) pbuf[wid][hi * 4 + rr][b16] = acc[rr];
    __syncthreads();

    if (wid == 0) {
      float pre[4];
#pragma unroll
      for (int q = 0; q < 4; ++q) {
        const int rl = q * 4 + ehl;
        pre[q] = bq[q] + gxr[q] + pbuf[0][rl][eb] + pbuf[1][rl][eb] +
                 pbuf[2][rl][eb] + pbuf[3][rl][eb];
      }
      float iv = fsig(pre[0]), fv = fsig(pre[1]);
      float gv = ftanh(pre[2]), ov = fsig(pre[3]);
      c_reg = fv * c_reg + iv * gv;
      float hn = ov * ftanh(c_reg);
      __hip_bfloat16 hh = __float2bfloat16(hn);
      int hb = (int)*(unsigned short*)&hh;
      int pr = __shfl_xor(hb, 16, 64);  // col ^ 1
      unsigned data32 = (unsigned)(unsigned short)hb | ((unsigned)(unsigned short)pr << 16);
      u64* ringo = (lay ? h1r : h0r) + (size_t)(t + 1) * 4096;
      if ((ehl & 1) == 0)
        agstore(ringo + (r8 * 2 + (ehl >> 1)) * 16 + eb,
                (u64)data32 | ((u64)(unsigned)(t + 1) << 32));
      if (lay) {
        unsigned d23 = (unsigned)__shfl((int)data32, eb + 32, 64);
        if (ehl == 0)
          *(u64*)(outs + ((size_t)(t * 16 + eb)) * 512 + hc0) = (u64)data32 | ((u64)d23 << 32);
      }
    }
    __syncthreads();  // pbuf reuse guard
  }
}

// ---------------- FC GEMM: out[b][t][32000] = outs[t*16+b][:] @ fcw^T + fcb (bf16 B) ----------------
__global__ __launch_bounds__(256) void fc_gemm(const __hip_bfloat16* __restrict__ A,
                                               const __hip_bfloat16* __restrict__ Bw,
                                               const float* __restrict__ bias,
                                               float* __restrict__ C) {
  __shared__ __align__(16) unsigned short lds_a[128 * 32];
  __shared__ __align__(16) unsigned short lds_b[128 * 32];
  const int tid = threadIdx.x;
  const int lane = tid & 63, wid = tid >> 6;
  const int m0 = blockIdx.y * 128, n0 = blockIdx.x * 128;
  const char* Ab = (const char*)A;
  const char* Bb = (const char*)Bw;
  const int ra = tid >> 2, cb = (tid & 3) * 16;
  f32x4 acc[4][4] = {};
  const int wm = (wid >> 1) * 64, wn = (wid & 1) * 64;
  const int fr = lane & 15, fk = (lane >> 4) * 8;
  for (int k0 = 0; k0 < HID; k0 += 32) {
    ld_lds16(Ab + (size_t)(m0 + ra) * 1024 + k0 * 2 + cb, (char*)lds_a + wid * 1024);
    ld_lds16(Ab + (size_t)(m0 + 64 + ra) * 1024 + k0 * 2 + cb, (char*)lds_a + 4096 + wid * 1024);
    ld_lds16(Bb + (size_t)(n0 + ra) * 1024 + k0 * 2 + cb, (char*)lds_b + wid * 1024);
    ld_lds16(Bb + (size_t)(n0 + 64 + ra) * 1024 + k0 * 2 + cb, (char*)lds_b + 4096 + wid * 1024);
    __syncthreads();
    bf16x8 af[4], bf[4];
#pragma unroll
    for (int i = 0; i < 4; ++i) af[i] = *(const bf16x8*)&lds_a[(wm + i * 16 + fr) * 32 + fk];
#pragma unroll
    for (int j = 0; j < 4; ++j) bf[j] = *(const bf16x8*)&lds_b[(wn + j * 16 + fr) * 32 + fk];
#pragma unroll
    for (int i = 0; i < 4; ++i)
#pragma unroll
      for (int j = 0; j < 4; ++j)
        acc[i][j] = __builtin_amdgcn_mfma_f32_16x16x32_bf16(af[i], bf[j], acc[i][j], 0, 0, 0);
    __syncthreads();
  }
  const int cr = (lane >> 4) * 4, cc2 = lane & 15;
  float bv[4];
#pragma unroll
  for (int jj = 0; jj < 4; ++jj) bv[jj] = bias[n0 + wn + jj * 16 + cc2];
#pragma unroll
  for (int i = 0; i < 4; ++i) {
#pragma unroll
    for (int jj = 0; jj < 4; ++jj) {
#pragma unroll
      for (int rr = 0; rr < 4; ++rr) {
        int tok = m0 + wm + i * 16 + cr + rr;      // = t*16 + b
        int orow = (tok & 15) * SEQ + (tok >> 4);  // = b*256 + t
        C[(size_t)orow * VOC + (n0 + wn + jj * 16 + cc2)] = acc[i][jj][rr] + bv[jj];
      }
    }
  }
}

extern "C" void kernel_launch(void* const* d_in, const int* in_sizes, int n_in,
                              void* d_out, int out_size, void* d_ws, size_t ws_size,
                              hipStream_t stream) {
  const int* x = (const int*)d_in[0];
  const float* emb = (const float*)d_in[1];
  const float* Wih = (const float*)d_in[2];
  const float* Whh = (const float*)d_in[3];
  const float* bias = (const float*)d_in[4];
  const float* fcw = (const float*)d_in[5];
  const float* fcb = (const float*)d_in[6];
  float* out = (float*)d_out;
  char* ws = (char*)d_ws;

  // ws layout (bytes), total 39,911,424 (R7-proven):
  //   [0, 8421376)           h0 ring: 257 slots x 32KB (u64 = 2 bf16 cols + tag)
  //   [8421376, 16842752)    h1 ring: 257 slots x 32KB
  //   [16842752, 18939904)   wih0 bf16 [2048][512]        (dead after gx_gemm)
  //   [18939904, 35717120)   gx bf16 [4096][2048]         (dead after lstm_k)
  //   [35717120, 39911424)   xe[4096][512] bf16 -> reused as outs after gx_gemm
  //   fcw_bf aliases [0, 32768000) (rings+wih0+gx head), written after lstm_k
  u64* h0r = (u64*)ws;
  u64* h1r = (u64*)(ws + 8421376);
  uint4* wih0_bf = (uint4*)(ws + 16842752);
  unsigned short* gxb = (unsigned short*)(ws + 18939904);
  unsigned short* xe = (unsigned short*)(ws + 35717120);
  unsigned short* outs = (unsigned short*)(ws + 35717120);
  uint4* fcw_bf = (uint4*)ws;

  hipMemsetAsync(ws, 0, 16842752, stream);  // both rings: tags=0 (slot0 = valid zero h[-1])
  embed_k<<<SEQ * NB, 64, 0, stream>>>(x, emb, xe);
  cvt_k<<<512, 256, 0, stream>>>(Wih, wih0_bf);  // layer-0 Wih (1M elems)
  gx_gemm<<<dim3(16, 32), 256, 0, stream>>>((const __hip_bfloat16*)xe,
                                            (const __hip_bfloat16*)wih0_bf, gxb);
  lstm_k<<<256, 256, 0, stream>>>(Wih, Whh, bias, gxb, h0r, h1r, outs);
  cvt_k<<<8000, 256, 0, stream>>>(fcw, fcw_bf);  // aliases rings/wih0/gx (dead after lstm)
  fc_gemm<<<dim3(250, 32), 256, 0, stream>>>((const __hip_bfloat16*)outs,
                                             (const __hip_bfloat16*)fcw_bf, fcb, out);
}